// Round 4
// baseline (455.702 us; speedup 1.0000x reference)
//
#include <hip/hip_runtime.h>
#include <stdint.h>

// ---------------------------------------------------------------------------
// RCNN post-process: refine bboxes, sort by score, greedy NMS (IoU >= 0.2),
// output = [refined boxes (N*4 floats)] ++ [keep mask as 0/1 floats (N)]
// ---------------------------------------------------------------------------

#define THR        0.2f
#define BORDER_EPS 1e-6f

typedef unsigned long long u64;
typedef unsigned int       u32;

__device__ __forceinline__ u64 rl64(u32 hi, u32 lo, int b) {
    return ((u64)__builtin_amdgcn_readlane(hi, (u32)b) << 32)
         |  (u64)__builtin_amdgcn_readlane(lo, (u32)b);
}

// ---------------- Kernel A: refine boxes (+ init pad boxes) ----------------
__global__ void k_refine(const float4* __restrict__ boxes,
                         const float4* __restrict__ deltas,
                         float4* __restrict__ out,        // d_out[0..4n)
                         float4* __restrict__ refined,    // ws
                         float4* __restrict__ sboxes,     // ws (pad init only)
                         int n, int npad) {
    int i = blockIdx.x * 256 + threadIdx.x;
    if (i >= n && i < npad) {
        sboxes[i] = make_float4(-4.0e6f, -4.0e6f, -3.999999e6f, -3.999999e6f);
    }
    if (i >= n) return;
    float4 b = boxes[i];
    float4 d = deltas[i];
    float x = __fmul_rn(__fadd_rn(b.x, b.z), 0.5f);
    float y = __fmul_rn(__fadd_rn(b.y, b.w), 0.5f);
    float w = __fsub_rn(b.z, b.x);
    float h = __fsub_rn(b.w, b.y);
    float nx = __fadd_rn(x, __fmul_rn(w, d.x));
    float ny = __fadd_rn(y, __fmul_rn(h, d.y));
    float ew = (float)exp((double)d.z);   // correctly-rounded f32 exp
    float eh = (float)exp((double)d.w);
    float nw = __fmul_rn(w, ew);
    float nh = __fmul_rn(h, eh);
    float hx = __fmul_rn(nw, 0.5f);
    float hy = __fmul_rn(nh, 0.5f);
    float4 o = make_float4(__fsub_rn(nx, hx), __fsub_rn(ny, hy),
                           __fadd_rn(nx, hx), __fadd_rn(ny, hy));
    refined[i] = o;
    out[i]     = o;
}

// ---------------- Kernel B: stable-descending rank + scatter ----------------
__global__ void k_rank(const float* __restrict__ scores,
                       const float4* __restrict__ refined,
                       float4* __restrict__ sboxes,
                       int* __restrict__ origIdx,
                       int n) {
    __shared__ __align__(16) float s[10016];
    int t = threadIdx.x;
    for (int idx = t; idx < n; idx += 256) s[idx] = scores[idx];
    __syncthreads();

    int i = blockIdx.x * 64 + (t >> 2);
    if (i >= n) return;
    int q = t & 3;
    float si = s[i];
    int j0 = (n * q) >> 2;
    int j1 = (n * (q + 1)) >> 2;
    int cnt = 0;

    int ja = (j0 + 3) & ~3;
    int jb = j1 & ~3;
    for (int j = j0; j < ja && j < j1; ++j) {
        float sj = s[j];
        cnt += (sj > si) || (sj == si && j < i);
    }
    const float4* sv = (const float4*)s;
    for (int j4 = ja >> 2; j4 < (jb >> 2); ++j4) {
        float4 v = sv[j4];
        int j = j4 << 2;
        cnt += (v.x > si) || (v.x == si && (j + 0) < i);
        cnt += (v.y > si) || (v.y == si && (j + 1) < i);
        cnt += (v.z > si) || (v.z == si && (j + 2) < i);
        cnt += (v.w > si) || (v.w == si && (j + 3) < i);
    }
    for (int j = jb > j0 ? jb : j0; j < j1; ++j) {
        float sj = s[j];
        cnt += (sj > si) || (sj == si && j < i);
    }
    cnt += __shfl_xor(cnt, 1, 64);
    cnt += __shfl_xor(cnt, 2, 64);
    if (q == 0) {
        sboxes[cnt]  = refined[i];
        origIdx[cnt] = i;
    }
}

// ---------------- Kernel C: suppression bitmask, column-per-thread ----------
// thread = one column (box in regs); rows broadcast from LDS.
// Decision: t = fma(uni, -THR, inter); sign decides unless |t| <= eps*uni
// (exact IEEE division fallback -> matches numpy bit-for-bit).
// Additionally writes the 3-word diagonal band per row into `band` so the
// scan kernel's per-group prefetch is coalesced.
#define M_COLS   256
#define M_RCHUNK 512
__global__ void k_mask(const float4* __restrict__ sboxes,
                       u64* __restrict__ mask,
                       u64* __restrict__ band,
                       int n, int npad, int words, int stride) {
    __shared__ __align__(16) float4 rowbox[M_RCHUNK];
    int tid = threadIdx.x;
    int c0  = blockIdx.x * M_COLS;
    int rc0 = blockIdx.y * M_RCHUNK;
    if (rc0 >= c0 + M_COLS || rc0 >= n) return;   // fully sub-diagonal / OOR

    int c = c0 + tid;
    float4 cbx = sboxes[c];
    float ca = __fmul_rn(__fsub_rn(cbx.z, cbx.x), __fsub_rn(cbx.w, cbx.y));
    int lane  = tid & 63;
    int wword = (c0 >> 6) + (tid >> 6);
    int cbase = wword << 6;

    int rlim_chunk = rc0 + M_RCHUNK; if (rlim_chunk > n) rlim_chunk = n;
    for (int j = tid; j < rlim_chunk - rc0; j += 256)
        rowbox[j] = sboxes[rc0 + j];
    __syncthreads();

    int rlim = rlim_chunk; if (rlim > cbase + 64) rlim = cbase + 64;
    for (int r = rc0; r < rlim; ++r) {
        float4 rb = rowbox[r - rc0];                       // uniform broadcast
        float ra = __fmul_rn(__fsub_rn(rb.z, rb.x), __fsub_rn(rb.w, rb.y));
        float xl = fmaxf(rb.x, cbx.x);
        float yt = fmaxf(rb.y, cbx.y);
        float xr = fminf(rb.z, cbx.z);
        float yb = fminf(rb.w, cbx.w);
        float iw = fmaxf(__fsub_rn(xr, xl), 0.0f);
        float ih = fmaxf(__fsub_rn(yb, yt), 0.0f);
        float inter = __fmul_rn(iw, ih);
        float uni = __fsub_rn(__fadd_rn(ra, ca), inter);
        float t = fmaf(uni, -THR, inter);                  // single-rounded
        bool sup = (t >= 0.0f);
        bool border = (fabsf(t) <= __fmul_rn(BORDER_EPS, uni));
        if (__any(border)) {                               // rare
            float q = inter / uni;                         // IEEE f32 div
            bool s2 = (q >= THR);
            sup = border ? s2 : sup;
        }
        u64 wvals = __ballot(sup);
        if (lane == 0) {
            u64 rmask = ~0ULL;
            if (r >= cbase) {
                int s = r - cbase;                         // 0..63
                rmask = (s >= 63) ? 0ULL : (~0ULL << (s + 1));
            }
            u64 v = wvals & rmask;
            mask[(size_t)r * stride + wword] = v;
            int d = wword - (r >> 6);
            if ((unsigned)d < 3u)                          // diagonal band
                band[(((size_t)(r >> 6) << 6) + (r & 63)) * 4 + d] = v;
        }
    }
}

// ---------------- Kernel D: grouped greedy scan, single barrier/group -------
// wave 0: per-group serial scan; D/E/F (words g,g+1,g+2 of the group's rows)
//   live per-lane, readlane-driven; Ered/Fred folded into the scan loop.
//   W(g) = wslot(covers groups <= g-3) | Ered(g-1) | Fred(g-2).
// waves 1-3: thread 64+w owns mask word w; kept-row full-row ORs are
//   software-pipelined one group ahead (OR prev loads, then issue next).
__global__ void k_scan(const u64* __restrict__ mask,
                       const u64* __restrict__ band,
                       const int* __restrict__ origIdx,
                       float* __restrict__ keep_out,
                       int n, int words, int stride) {
    __shared__ u64 ks[160];
    __shared__ u64 wslot[2];
    int tid  = threadIdx.x;
    int lane = tid & 63;
    int wv   = tid >> 6;
    int owner = tid - 64;          // word owned by waves 1-3

    // wave 0 state
    u64 W = 0, D = 0, E = 0, F = 0;
    u64 Ered_m1 = 0, Fred_m1 = 0, Fred_m2 = 0;
    if (wv == 0) {
        const u64* bp = band + ((size_t)lane << 2);   // group 0
        D = bp[0]; E = bp[1]; F = bp[2];
    }
    // waves 1-3 pipeline state
    u64 rem = 0;
    int pcnt = 0;
    u64 pv0=0,pv1=0,pv2=0,pv3=0,pv4=0,pv5=0,pv6=0,pv7=0;
    u64 pv8=0,pv9=0,pv10=0,pv11=0,pv12=0,pv13=0,pv14=0,pv15=0;

    for (int g = 0; g < words; ++g) {
        if (wv == 0) {
            // ---- assemble W(g): lag-3 rem + the two ahead-columns ----
            if (g > 0) W = wslot[g & 1] | Ered_m1 | Fred_m2;
            int rbase = g << 6;
            int nv = n - rbase; if (nv > 64) nv = 64;
            u64 validmask = (nv >= 64) ? ~0ULL : ((1ULL << nv) - 1ULL);
            u64 Wl = W | ~validmask;
            u32 dlo = (u32)D, dhi = (u32)(D >> 32);
            u32 elo = (u32)E, ehi = (u32)(E >> 32);
            u32 flo = (u32)F, fhi = (u32)(F >> 32);
            u64 cand = ~Wl;
            u64 er = 0, fr = 0;
            while (cand) {                    // iterates exactly the kept rows
                int b = __builtin_ctzll(cand);
                u64 Db = rl64(dhi, dlo, b);
                er |= rl64(ehi, elo, b);
                fr |= rl64(fhi, flo, b);
                Wl  |= Db;
                cand &= ~(Db | (1ULL << b));
            }
            u64 K = validmask & ~Wl;
            if (lane == 0) ks[g] = K;
            Fred_m2 = Fred_m1; Fred_m1 = fr; Ered_m1 = er;
            // ---- prefetch next group's band (consumed next iteration) ----
            if (g + 1 < words) {
                const u64* bp = band + (((size_t)(g + 1) << 6) + lane) * 4;
                D = bp[0]; E = bp[1]; F = bp[2];
            }
        } else if (owner < words) {
            // ---- OR pending loads (kept rows of group g-2) ----
            rem |= (pcnt > 0  ? pv0  : 0) | (pcnt > 1  ? pv1  : 0)
                 | (pcnt > 2  ? pv2  : 0) | (pcnt > 3  ? pv3  : 0)
                 | (pcnt > 4  ? pv4  : 0) | (pcnt > 5  ? pv5  : 0)
                 | (pcnt > 6  ? pv6  : 0) | (pcnt > 7  ? pv7  : 0)
                 | (pcnt > 8  ? pv8  : 0) | (pcnt > 9  ? pv9  : 0)
                 | (pcnt > 10 ? pv10 : 0) | (pcnt > 11 ? pv11 : 0)
                 | (pcnt > 12 ? pv12 : 0) | (pcnt > 13 ? pv13 : 0)
                 | (pcnt > 14 ? pv14 : 0) | (pcnt > 15 ? pv15 : 0);
            // ---- issue loads for kept rows of group g-1 ----
            u64 kk = (g > 0) ? ks[g - 1] : 0ULL;
            pcnt = 0;
            if (kk) {
                int np = __builtin_popcountll(kk);
                const u64* bp = mask + ((size_t)(g - 1) << 6) * stride + owner;
                u64 k2 = kk;
                int b0,b1,b2,b3,b4,b5,b6,b7,b8,b9,b10,b11,b12,b13,b14,b15;
#define EXTR(bi) bi = k2 ? (int)__builtin_ctzll(k2) : bprev; \
                 bprev = bi; k2 &= k2 - 1;
                int bprev = 0;
                EXTR(b0)  EXTR(b1)  EXTR(b2)  EXTR(b3)
                EXTR(b4)  EXTR(b5)  EXTR(b6)  EXTR(b7)
                EXTR(b8)  EXTR(b9)  EXTR(b10) EXTR(b11)
                EXTR(b12) EXTR(b13) EXTR(b14) EXTR(b15)
#undef EXTR
                pv0  = bp[(size_t)b0  * stride];
                pv1  = bp[(size_t)b1  * stride];
                pv2  = bp[(size_t)b2  * stride];
                pv3  = bp[(size_t)b3  * stride];
                pv4  = bp[(size_t)b4  * stride];
                pv5  = bp[(size_t)b5  * stride];
                pv6  = bp[(size_t)b6  * stride];
                pv7  = bp[(size_t)b7  * stride];
                pv8  = bp[(size_t)b8  * stride];
                pv9  = bp[(size_t)b9  * stride];
                pv10 = bp[(size_t)b10 * stride];
                pv11 = bp[(size_t)b11 * stride];
                pv12 = bp[(size_t)b12 * stride];
                pv13 = bp[(size_t)b13 * stride];
                pv14 = bp[(size_t)b14 * stride];
                pv15 = bp[(size_t)b15 * stride];
                pcnt = np > 16 ? 16 : np;
                if (np > 16) {                 // rare sync remainder
                    while (k2) {
                        int bb = (int)__builtin_ctzll(k2); k2 &= k2 - 1;
                        rem |= bp[(size_t)bb * stride];
                    }
                }
            }
            // ---- publish rem for word g+1 (covers groups <= g-2) ----
            if (owner == g + 1) wslot[(g + 1) & 1] = rem;
        }
        __syncthreads();
    }

    // final scatter (ks complete after last barrier)
    for (int r = tid; r < n; r += 256) {
        int bit = (int)((ks[r >> 6] >> (r & 63)) & 1ULL);   // 1 = kept
        keep_out[origIdx[r]] = bit ? 1.0f : 0.0f;
    }
}

// ---------------------------------------------------------------------------
extern "C" void kernel_launch(void* const* d_in, const int* in_sizes, int n_in,
                              void* d_out, int out_size, void* d_ws, size_t ws_size,
                              hipStream_t stream) {
    const float4* boxes  = (const float4*)d_in[0];
    const float4* deltas = (const float4*)d_in[1];
    const float*  scores = (const float*)d_in[2];
    int n = in_sizes[2];                        // 10000
    int words  = (n + 63) >> 6;                 // 157
    int stride = (words + 3) & ~3;              // 160 (u64 words per row)
    int npad   = ((n + M_COLS - 1) / M_COLS) * M_COLS;  // 10240

    char* ws = (char*)d_ws;
    float4* refined = (float4*)ws;                                  // npad*16
    float4* sboxes  = (float4*)(ws + (size_t)npad * 16);            // npad*16
    int*    origIdx = (int*)(ws + (size_t)npad * 32);               // n*4
    size_t  moff    = ((size_t)npad * 32 + (size_t)n * 4 + 1023) & ~(size_t)1023;
    u64*    mask    = (u64*)(ws + moff);                            // n*stride*8
    size_t  msize   = (size_t)n * stride * 8;
    u64*    band    = (u64*)(ws + moff + msize);                    // words*64*4*8

    float* out = (float*)d_out;

    k_refine<<<(npad + 255) / 256, 256, 0, stream>>>(
        boxes, deltas, (float4*)out, refined, sboxes, n, npad);
    k_rank<<<(n + 63) / 64, 256, 0, stream>>>(scores, refined, sboxes, origIdx, n);
    dim3 mgrid(npad / M_COLS, (n + M_RCHUNK - 1) / M_RCHUNK);
    k_mask<<<mgrid, 256, 0, stream>>>(sboxes, mask, band, n, npad, words, stride);
    k_scan<<<1, 256, 0, stream>>>(mask, band, origIdx, out + (size_t)n * 4,
                                  n, words, stride);
}